// Round 13
// baseline (5931.828 us; speedup 1.0000x reference)
//
#include <hip/hip_runtime.h>

typedef __bf16 bf16x8 __attribute__((ext_vector_type(8)));
typedef float f32x4 __attribute__((ext_vector_type(4)));
typedef unsigned short u16;
typedef unsigned long long u64;

#define NSTEP 512
#define WLDS_BYTES 110592   // [48 kk][2 nt][16 rb][36] u16

#define AL(p)   __hip_atomic_load((p), __ATOMIC_RELAXED, __HIP_MEMORY_SCOPE_AGENT)
#define AS(p,v) __hip_atomic_store((p), (v), __ATOMIC_RELAXED, __HIP_MEMORY_SCOPE_AGENT)

__device__ __forceinline__ u16 f2bf(float f) {
  union { float f; unsigned u; } x; x.f = f;
  return (u16)((x.u + 0x7fffu + ((x.u >> 16) & 1u)) >> 16);
}

// zero h slabs (2 groups x 3 bufs x 32x1024 bf16) + flags
__global__ void prep_kernel(u64* __restrict__ H, int* __restrict__ bar) {
  int i = blockIdx.x * blockDim.x + threadIdx.x;
  if (i < 49152) H[i] = 0;
  if (i < 8256) bar[i] = 0;
}

// A1[t*64+b][512] bf16 embedding gather
__global__ void gather_kernel(const int* __restrict__ sent, const float* __restrict__ emb,
                              u16* __restrict__ A1) {
  int row = blockIdx.x * 4 + (threadIdx.x >> 6);   // t*64+b
  int lane = threadIdx.x & 63;
  int t = row >> 6, b = row & 63;
  int idx = sent[b * 512 + t];
  const float* src = emb + (size_t)idx * 512 + lane * 8;
  u16* dst = A1 + (size_t)row * 512 + lane * 8;
  #pragma unroll
  for (int k = 0; k < 8; ++k) dst[k] = f2bf(src[k]);
}

// 256 WGs x 256 thr = 2 INDEPENDENT batch groups x 128 WGs.
// Group gb (batch rows gb*32..+32): own h slab, own 128 epoch flags, own barrier.
// WG jc in group owns h cols [jc*8, jc*8+8); waves = (mh: 16-row half) x (nt: 4-col tile).
// Gate packing per n-tile: rb = g*4+nn = lr (r12-identical per-wave structure).
// Weights (x K=512 + h K=1024) in 108 KB padded dynamic LDS.
__global__ void __launch_bounds__(256, 1)
lstm_kernel(const u16* __restrict__ A1,
            const float* __restrict__ wih, const float* __restrict__ whh,
            const float* __restrict__ bih, const float* __restrict__ bhh,
            u16* __restrict__ H, float* __restrict__ out, int* __restrict__ bar) {
  extern __shared__ u16 wlds[];             // [48][2][16][36] u16 = 110592 B
  __shared__ alignas(8) u16 hx[4][16][4];   // per-wave h-store packing bounce

  const int j   = blockIdx.x;
  const int gb  = j >> 7;              // batch group 0..1
  const int jc  = j & 127;             // col-block in group
  const int tid = threadIdx.x;
  const int w   = tid >> 6;            // wave 0..3
  const int mh  = w >> 1;              // batch half (16 rows)
  const int nt  = w & 1;               // 4-col tile
  const int l   = tid & 63;
  const int lr  = l & 15, lk = l >> 4;
  const int g   = lr >> 2, nn = lr & 3;

  // ---- stage weights fp32->bf16 into padded dynamic LDS (once) ----
  for (int task = tid; task < 6144; task += 256) {
    int kk = task >> 7;                 // K chunk of 32 (0..47)
    int rem = task & 127;
    int ntt = rem >> 6;
    int rem2 = rem & 63;
    int rb = rem2 >> 2, q = rem2 & 3;
    int row = (rb >> 2) * 1024 + jc * 8 + ntt * 4 + (rb & 3);
    const float* src = (kk < 16) ? (wih + (size_t)row * 512 + kk * 32 + q * 8)
                                 : (whh + (size_t)row * 1024 + (kk - 16) * 32 + q * 8);
    u16* dst = wlds + (size_t)((kk * 2 + ntt) * 16 + rb) * 36 + q * 8;
    #pragma unroll
    for (int e = 0; e < 8; ++e) dst[e] = f2bf(src[e]);
  }
  __syncthreads();

  const int wrow = g * 1024 + jc * 8 + nt * 4 + nn;
  const float bias = bih[wrow] + bhh[wrow];
  const float sca = (g == 2) ? 2.f : 1.f;   // tanh-as-sigmoid scaling
  const float bd  = (g == 2) ? -1.f : 0.f;
  const int arow = gb * 32 + mh * 16 + lr;  // global batch row for A fragments
  const u16* bx = wlds + (size_t)(nt * 16 + lr) * 36 + lk * 8;  // + kk*1152

  u16* const hgrp = H + (size_t)gb * 98304;         // group h slab (3 bufs x 32768)
  int* const fgrp = bar + gb * 4096;                // group flags (128 x 32-int stride)

  float cst[4] = {0.f, 0.f, 0.f, 0.f};

  union AF { bf16x8 v; u64 q[2]; };

#define LD8(BUF, CH)                                                        \
  { _Pragma("unroll")                                                       \
    for (int r = 0; r < 8; ++r) {                                           \
      const u64* p = (const u64*)(hp + (CH) * 256 + r * 32);                \
      BUF[r].q[0] = AL(p); BUF[r].q[1] = AL(p + 1);                         \
    } }
#define MM8(ACC, BUF, CH)                                                   \
  { _Pragma("unroll")                                                       \
    for (int r = 0; r < 8; ++r) {                                           \
      bf16x8 b = *(const bf16x8*)(bx + (size_t)(16 + (CH) * 8 + r) * 1152); \
      ACC = __builtin_amdgcn_mfma_f32_16x16x32_bf16(BUF[r].v, b, ACC, 0, 0, 0); \
    } }

  // x-projection for t=0 (A1 prefetch + 16 MFMAs)
  f32x4 acx;
  {
    bf16x8 ax[16];
    const u16* apre = A1 + (size_t)arow * 512 + lk * 8;
    #pragma unroll
    for (int kk = 0; kk < 16; ++kk) ax[kk] = *(const bf16x8*)(apre + kk * 32);
    f32x4 an = { bias, bias, bias, bias };
    #pragma unroll
    for (int kk = 0; kk < 16; ++kk) {
      bf16x8 b = *(const bf16x8*)(bx + (size_t)kk * 1152);
      an = __builtin_amdgcn_mfma_f32_16x16x32_bf16(ax[kk], b, an, 0, 0, 0);
    }
    acx = an;
  }

  #pragma unroll 1
  for (int t = 0; t < NSTEP; ++t) {
    AF ha[8], hb[8];
    const u16* hp = hgrp + (size_t)(t % 3) * 32768 + (size_t)(mh * 16 + lr) * 1024 + lk * 8;
    // h-projection: double-buffered 8-fragment chunks, 2 acc chains
    LD8(ha, 0); LD8(hb, 1);
    f32x4 acc = acx;                    // bias + x already in
    f32x4 ach = { 0.f, 0.f, 0.f, 0.f };
    MM8(acc, ha, 0);
    LD8(ha, 2); MM8(ach, hb, 1);
    LD8(hb, 3); MM8(acc, ha, 2);
    MM8(ach, hb, 3);
    #pragma unroll
    for (int r = 0; r < 4; ++r) acc[r] += ach[r];

    // activations + state update; lanes lr<4 own (rows lk*4+r, col nt*4+lr)
    float hv4[4], cn4[4];
    #pragma unroll
    for (int r = 0; r < 4; ++r) {
      float act = sca / (1.f + __expf(-sca * acc[r])) + bd;  // sigmoid / tanh
      float gg = __shfl_xor(act, 8);
      float ff = __shfl_xor(act, 4);
      float oo = __shfl_xor(act, 12);
      float cn = ff * cst[r] + act * gg;   // act = i at lanes lr<4
      cst[r] = cn;
      float tc = 2.f / (1.f + __expf(-2.f * cn)) - 1.f;
      hv4[r] = oo * tc;
      cn4[r] = cn;
    }

    if (t == NSTEP - 1) {
      if (lr < 4) {
        #pragma unroll
        for (int r = 0; r < 4; ++r) {
          int R = gb * 32 + mh * 16 + lk * 4 + r;
          int C = jc * 8 + nt * 4 + lr;
          out[(size_t)R * 1024 + C]          = hv4[r];
          out[65536 + (size_t)R * 1024 + C]  = hv4[r];
          out[131072 + (size_t)R * 1024 + C] = cn4[r];
        }
      }
    } else {
      // pack wave's 16x4 h tile -> one 8B agent-scope store per row
      if (lr < 4) {
        #pragma unroll
        for (int r = 0; r < 4; ++r) hx[w][lk * 4 + r][lr] = f2bf(hv4[r]);
      }
      __syncthreads();
      if (l < 16) {
        u64 pk = *(const u64*)(&hx[w][l][0]);
        u16* hw = hgrp + (size_t)((t + 1) % 3) * 32768
                       + (size_t)(mh * 16 + l) * 1024 + jc * 8 + nt * 4;
        AS((u64*)hw, pk);
      }
      // h stores reach coherence point before the arrival flag
      asm volatile("s_waitcnt vmcnt(0)" ::: "memory");
      __syncthreads();
      const int t1 = t + 1;
      if (tid == 0) AS(&fgrp[jc * 32], t1);        // publish epoch (monotonic)
      // wait window: A1 prefetch + x-projection for t1 (fills the tail)
      {
        bf16x8 ax[16];
        const u16* apre = A1 + ((size_t)t1 * 64 + arow) * 512 + lk * 8;
        #pragma unroll
        for (int kk = 0; kk < 16; ++kk) ax[kk] = *(const bf16x8*)(apre + kk * 32);
        f32x4 an = { bias, bias, bias, bias };
        #pragma unroll
        for (int kk = 0; kk < 16; ++kk) {
          bf16x8 b = *(const bf16x8*)(bx + (size_t)kk * 1152);
          an = __builtin_amdgcn_mfma_f32_16x16x32_bf16(ax[kk], b, an, 0, 0, 0);
        }
        acx = an;
      }
      // direct wait on OWN group's 128 producer flags (1 poller each)
      if (tid < 128) {
        while (AL(&fgrp[tid * 32]) < t1) __builtin_amdgcn_s_sleep(1);
      }
      __syncthreads();
    }
  }
#undef LD8
#undef MM8
}

extern "C" void kernel_launch(void* const* d_in, const int* in_sizes, int n_in,
                              void* d_out, int out_size, void* d_ws, size_t ws_size,
                              hipStream_t stream) {
  const int*   sent = (const int*)d_in[0];
  const float* emb  = (const float*)d_in[1];
  const float* w_ih = (const float*)d_in[2];
  const float* w_hh = (const float*)d_in[3];
  const float* b_ih = (const float*)d_in[4];
  const float* b_hh = (const float*)d_in[5];
  float* out = (float*)d_out;

  char* ws = (char*)d_ws;
  u16* A1 = (u16*)ws;                            // 32 MiB
  u16* H  = (u16*)(ws + 33554432);               // 2 groups x 3 x 64 KiB = 384 KiB
  int* bar = (int*)(ws + 33554432 + 393216);     // 2 x 128 epoch flags

  prep_kernel<<<256, 256, 0, stream>>>((u64*)H, bar);
  gather_kernel<<<8192, 256, 0, stream>>>(sent, emb, A1);

  (void)hipFuncSetAttribute((const void*)lstm_kernel,
                            hipFuncAttributeMaxDynamicSharedMemorySize, WLDS_BYTES);

  void* args[] = { (void*)&A1, (void*)&w_ih, (void*)&w_hh,
                   (void*)&b_ih, (void*)&b_hh, (void*)&H, (void*)&out, (void*)&bar };
  hipError_t err = hipLaunchCooperativeKernel((void*)lstm_kernel, dim3(256), dim3(256),
                                              args, WLDS_BYTES, stream);
  if (err != hipSuccess) {
    // barriers are custom per-group; plain launch fine when all WGs co-resident
    lstm_kernel<<<dim3(256), dim3(256), WLDS_BYTES, stream>>>(A1, w_ih, w_hh,
                                                              b_ih, b_hh, H, out, bar);
  }
}

// Round 15
// 4318.875 us; speedup vs baseline: 1.3735x; 1.3735x over previous
//
#include <hip/hip_runtime.h>

typedef __bf16 bf16x8 __attribute__((ext_vector_type(8)));
typedef float f32x4 __attribute__((ext_vector_type(4)));
typedef unsigned short u16;
typedef unsigned long long u64;

#define NSTEP 512

#define AL(p)   __hip_atomic_load((p), __ATOMIC_RELAXED, __HIP_MEMORY_SCOPE_AGENT)
#define AS(p,v) __hip_atomic_store((p), (v), __ATOMIC_RELAXED, __HIP_MEMORY_SCOPE_AGENT)

__device__ __forceinline__ u16 f2bf(float f) {
  union { float f; unsigned u; } x; x.f = f;
  return (u16)((x.u + 0x7fffu + ((x.u >> 16) & 1u)) >> 16);
}

// zero h buffer 0 + 1024 per-wave epoch flags (every call -> deterministic replays)
__global__ void prep_kernel(u64* __restrict__ H0, int* __restrict__ F) {
  int i = blockIdx.x * blockDim.x + threadIdx.x;
  if (i < 16384) AS(H0 + i, 0ULL);
  if (i < 32768) AS(&F[i], 0);
}

// A1[t*64+b][512] bf16 embedding gather
__global__ void gather_kernel(const int* __restrict__ sent, const float* __restrict__ emb,
                              u16* __restrict__ A1) {
  int row = blockIdx.x * 4 + (threadIdx.x >> 6);   // t*64+b
  int lane = threadIdx.x & 63;
  int t = row >> 6, b = row & 63;
  int idx = sent[b * 512 + t];
  const float* src = emb + (size_t)idx * 512 + lane * 8;
  u16* dst = A1 + (size_t)row * 512 + lane * 8;
  #pragma unroll
  for (int k = 0; k < 8; ++k) dst[k] = f2bf(src[k]);
}

// 256 WGs x 256 thr. WG j owns h cols [j*4,j*4+4), gates packed rb = g*4+nn = lr.
// Weights in padded LDS. h: per-step FRESH buffers (never reused) — producers
// store sc1 (straight to L3), consumers read CACHED after observing the
// producer's epoch flag (r12-proven visibility pair).
// NO grid barrier: 1024 (WG, wave) actors; wave publishes flag[(j*4+w)] = t+1
// after its own vmcnt(0); consumer wave polls the 64 producer flags of each
// K-chunk right before that chunk's MFMAs (64 lanes, 1 flag each).
__global__ void __launch_bounds__(256, 2)
lstm_kernel(const u16* __restrict__ A1,
            const float* __restrict__ wih, const float* __restrict__ whh,
            const float* __restrict__ bih, const float* __restrict__ bhh,
            u16* __restrict__ H, float* __restrict__ out, int* __restrict__ F) {
  __shared__ u16 wlds[48 * 16 * 36];        // 55296 B, stride-36 pad
  __shared__ alignas(8) u16 hx[4][16][4];   // per-wave h-store packing bounce

  const int j   = blockIdx.x;
  const int tid = threadIdx.x;
  const int w   = tid >> 6;            // wave = batch tile 0..3
  const int l   = tid & 63;
  const int lr  = l & 15, lk = l >> 4;
  const int g   = lr >> 2, nn = lr & 3;
  const int wrow = g * 1024 + j * 4 + nn;

  // ---- stage ALL weights fp32->bf16 into padded LDS (once) ----
  for (int task = tid; task < 3072; task += 256) {
    int kk = task >> 6;                 // K chunk of 32 (0..47)
    int rem = task & 63;
    int rb = rem >> 2, q = rem & 3;
    int row = (rb >> 2) * 1024 + j * 4 + (rb & 3);
    const float* src = (kk < 16) ? (wih + (size_t)row * 512 + kk * 32 + q * 8)
                                 : (whh + (size_t)row * 1024 + (kk - 16) * 32 + q * 8);
    u16* dst = wlds + (kk * 16 + rb) * 36 + q * 8;
    #pragma unroll
    for (int e = 0; e < 8; ++e) dst[e] = f2bf(src[e]);
  }
  __syncthreads();

  const float bias = bih[wrow] + bhh[wrow];
  const float sca = (g == 2) ? 2.f : 1.f;   // tanh-as-sigmoid scaling
  const float bd  = (g == 2) ? -1.f : 0.f;
  const int arow = w * 16 + lr;             // batch row for A fragments
  const u16* bx = wlds + lr * 36 + lk * 8;  // + kk*576 per K chunk

  float cst[4] = {0.f, 0.f, 0.f, 0.f};

  // prefetch A1 fragments for t=0
  bf16x8 ax[16];
  {
    const u16* apre = A1 + (size_t)arow * 512 + lk * 8;
    #pragma unroll
    for (int kk = 0; kk < 16; ++kk) ax[kk] = *(const bf16x8*)(apre + kk * 32);
  }

  union AF { bf16x8 v; u64 q[2]; };

  // flag of (producer WG p, wave w) at F[p*128 + w*32]
#define WAITCH(c, T)                                                        \
  { const int* fp = F + ((c) * 64 + l) * 128 + w * 32;                      \
    while (AL(fp) < (T)) __builtin_amdgcn_s_sleep(1); }
#define LD8(BUF, CH)                                                        \
  { _Pragma("unroll")                                                       \
    for (int r = 0; r < 8; ++r)                                             \
      BUF[r].v = *(const bf16x8*)(hp + (CH) * 256 + r * 32); }
#define MM8(BUF, W0)                                                        \
  { _Pragma("unroll")                                                       \
    for (int r = 0; r < 8; ++r) {                                           \
      bf16x8 b = *(const bf16x8*)(bx + ((W0) + r) * 576);                   \
      acc = __builtin_amdgcn_mfma_f32_16x16x32_bf16(BUF[r].v, b, acc, 0, 0, 0); \
    } }

  #pragma unroll 1
  for (int t = 0; t < NSTEP; ++t) {
    AF ha[8], hb[8];
    const u16* hp = H + (size_t)t * 65536 + (size_t)arow * 1024 + lk * 8;
    // chunk 0/1: wait producers (64 lanes x 1 flag), then issue cached loads
    WAITCH(0, t);
    LD8(ha, 0);
    WAITCH(1, t);
    LD8(hb, 1);
    // x-projection from prefetched ax (covers the h fills)
    f32x4 acc = { bias, bias, bias, bias };
    #pragma unroll
    for (int kk = 0; kk < 16; ++kk) {
      bf16x8 b = *(const bf16x8*)(bx + kk * 576);
      acc = __builtin_amdgcn_mfma_f32_16x16x32_bf16(ax[kk], b, acc, 0, 0, 0);
    }
    // h-projection: chunk waits woven into the MFMA chain
    MM8(ha, 16);
    WAITCH(2, t); LD8(ha, 2);
    MM8(hb, 24);
    WAITCH(3, t); LD8(hb, 3);
    MM8(ha, 32);
    MM8(hb, 40);

    // activations + state update; lanes lr<4 own (rows lk*4+r, col lr)
    float hv4[4], cn4[4];
    #pragma unroll
    for (int r = 0; r < 4; ++r) {
      float xv = acc[r];
      float act = sca / (1.f + __expf(-sca * xv)) + bd;  // sigmoid / tanh
      float gg = __shfl_xor(act, 8);
      float ff = __shfl_xor(act, 4);
      float oo = __shfl_xor(act, 12);
      float cn = ff * cst[r] + act * gg;   // act = i at lanes lr<4
      cst[r] = cn;
      float tc = 2.f / (1.f + __expf(-2.f * cn)) - 1.f;
      hv4[r] = oo * tc;
      cn4[r] = cn;
    }

    if (t == NSTEP - 1) {
      if (lr < 4) {
        #pragma unroll
        for (int r = 0; r < 4; ++r) {
          int R = w * 16 + lk * 4 + r;
          out[(size_t)R * 1024 + j * 4 + lr]          = hv4[r];
          out[65536 + (size_t)R * 1024 + j * 4 + lr]  = hv4[r];
          out[131072 + (size_t)R * 1024 + j * 4 + lr] = cn4[r];
        }
      }
    } else {
      // pack wave's 16x4 h tile in LDS (same-wave ds ops are in-order; no barrier)
      if (lr < 4) {
        #pragma unroll
        for (int r = 0; r < 4; ++r) hx[w][lk * 4 + r][lr] = f2bf(hv4[r]);
      }
      if (l < 16) {
        u64 pk = *(const u64*)(&hx[w][l][0]);
        u16* hw = H + (size_t)(t + 1) * 65536 + (size_t)(w * 16 + l) * 1024 + j * 4;
        AS((u64*)hw, pk);
      }
      // this wave's h stores reach L3, then publish this wave's epoch flag
      asm volatile("s_waitcnt vmcnt(0)" ::: "memory");
      if (l == 0) AS(F + j * 128 + w * 32, t + 1);
      // prefetch A1 for t+1 (fills under next step's chunk-0 wait)
      {
        const u16* apre = A1 + ((size_t)(t + 1) * 64 + arow) * 512 + lk * 8;
        #pragma unroll
        for (int kk = 0; kk < 16; ++kk) ax[kk] = *(const bf16x8*)(apre + kk * 32);
      }
    }
  }
#undef WAITCH
#undef LD8
#undef MM8
}

extern "C" void kernel_launch(void* const* d_in, const int* in_sizes, int n_in,
                              void* d_out, int out_size, void* d_ws, size_t ws_size,
                              hipStream_t stream) {
  const int*   sent = (const int*)d_in[0];
  const float* emb  = (const float*)d_in[1];
  const float* w_ih = (const float*)d_in[2];
  const float* w_hh = (const float*)d_in[3];
  const float* b_ih = (const float*)d_in[4];
  const float* b_hh = (const float*)d_in[5];
  float* out = (float*)d_out;

  // A1 32Mi | H 512 x 128Ki = 64Mi | F 128Ki  (~96.2 MiB; r12 proved >=96.1 MiB)
  char* ws = (char*)d_ws;
  u16* A1 = (u16*)ws;
  u16* H  = (u16*)(ws + 33554432);
  int* F  = (int*)(ws + 33554432 + 67108864);

  prep_kernel<<<256, 256, 0, stream>>>((u64*)H, F);
  gather_kernel<<<8192, 256, 0, stream>>>(sent, emb, A1);

  void* args[] = { (void*)&A1, (void*)&w_ih, (void*)&w_hh,
                   (void*)&b_ih, (void*)&b_hh, (void*)&H, (void*)&out, (void*)&F };
  hipError_t err = hipLaunchCooperativeKernel((void*)lstm_kernel, dim3(256), dim3(256),
                                              args, 0, stream);
  if (err != hipSuccess) {
    // dataflow kernel needs co-residency only; 2-blocks/CU envelope on 256 CUs
    lstm_kernel<<<dim3(256), dim3(256), 0, stream>>>(A1, w_ih, w_hh, b_ih, b_hh,
                                                     H, out, F);
  }
}

// Round 16
// 4272.319 us; speedup vs baseline: 1.3884x; 1.0109x over previous
//
#include <hip/hip_runtime.h>

typedef __bf16 bf16x8 __attribute__((ext_vector_type(8)));
typedef float f32x4 __attribute__((ext_vector_type(4)));
typedef unsigned short u16;
typedef unsigned long long u64;

#define NSTEP 512

#define AL(p)   __hip_atomic_load((p), __ATOMIC_RELAXED, __HIP_MEMORY_SCOPE_AGENT)
#define AS(p,v) __hip_atomic_store((p), (v), __ATOMIC_RELAXED, __HIP_MEMORY_SCOPE_AGENT)

__device__ __forceinline__ u16 f2bf(float f) {
  union { float f; unsigned u; } x; x.f = f;
  return (u16)((x.u + 0x7fffu + ((x.u >> 16) & 1u)) >> 16);
}

// zero h buffer 0 + 1024 per-wave epoch flags (every call -> deterministic replays)
__global__ void prep_kernel(u64* __restrict__ H0, int* __restrict__ F) {
  int i = blockIdx.x * blockDim.x + threadIdx.x;
  if (i < 16384) AS(H0 + i, 0ULL);
  if (i < 32768) AS(&F[i], 0);
}

// A1[t*64+b][512] bf16 embedding gather
__global__ void gather_kernel(const int* __restrict__ sent, const float* __restrict__ emb,
                              u16* __restrict__ A1) {
  int row = blockIdx.x * 4 + (threadIdx.x >> 6);   // t*64+b
  int lane = threadIdx.x & 63;
  int t = row >> 6, b = row & 63;
  int idx = sent[b * 512 + t];
  const float* src = emb + (size_t)idx * 512 + lane * 8;
  u16* dst = A1 + (size_t)row * 512 + lane * 8;
  #pragma unroll
  for (int k = 0; k < 8; ++k) dst[k] = f2bf(src[k]);
}

// 256 WGs x 256 thr. WG j owns h cols [j*4,j*4+4), gates packed rb = g*4+nn = lr.
// Weights in padded LDS. h: per-step FRESH buffers (never reused) — producers
// store sc1 (straight to L3), consumers read CACHED after observing the
// producer's epoch flag (r12/r15-proven visibility pair).
// NO grid barrier (r15). NEW (r16): the 4 per-chunk flag waits are issued as 4
// CONCURRENT loads at loop start (1 far RT instead of 4 in the fast path);
// per-chunk readiness checks are register compares, laggards re-poll woven
// into the MFMA chain.
__global__ void __launch_bounds__(256, 2)
lstm_kernel(const u16* __restrict__ A1,
            const float* __restrict__ wih, const float* __restrict__ whh,
            const float* __restrict__ bih, const float* __restrict__ bhh,
            u16* __restrict__ H, float* __restrict__ out, int* __restrict__ F) {
  __shared__ u16 wlds[48 * 16 * 36];        // 55296 B, stride-36 pad
  __shared__ alignas(8) u16 hx[4][16][4];   // per-wave h-store packing bounce

  const int j   = blockIdx.x;
  const int tid = threadIdx.x;
  const int w   = tid >> 6;            // wave = batch tile 0..3
  const int l   = tid & 63;
  const int lr  = l & 15, lk = l >> 4;
  const int g   = lr >> 2, nn = lr & 3;
  const int wrow = g * 1024 + j * 4 + nn;

  // ---- stage ALL weights fp32->bf16 into padded LDS (once) ----
  for (int task = tid; task < 3072; task += 256) {
    int kk = task >> 6;                 // K chunk of 32 (0..47)
    int rem = task & 63;
    int rb = rem >> 2, q = rem & 3;
    int row = (rb >> 2) * 1024 + j * 4 + (rb & 3);
    const float* src = (kk < 16) ? (wih + (size_t)row * 512 + kk * 32 + q * 8)
                                 : (whh + (size_t)row * 1024 + (kk - 16) * 32 + q * 8);
    u16* dst = wlds + (kk * 16 + rb) * 36 + q * 8;
    #pragma unroll
    for (int e = 0; e < 8; ++e) dst[e] = f2bf(src[e]);
  }
  __syncthreads();

  const float bias = bih[wrow] + bhh[wrow];
  const float sca = (g == 2) ? 2.f : 1.f;   // tanh-as-sigmoid scaling
  const float bd  = (g == 2) ? -1.f : 0.f;
  const int arow = w * 16 + lr;             // batch row for A fragments
  const u16* bx = wlds + lr * 36 + lk * 8;  // + kk*576 per K chunk

  float cst[4] = {0.f, 0.f, 0.f, 0.f};

  // prefetch A1 fragments for t=0
  bf16x8 ax[16];
  {
    const u16* apre = A1 + (size_t)arow * 512 + lk * 8;
    #pragma unroll
    for (int kk = 0; kk < 16; ++kk) ax[kk] = *(const bf16x8*)(apre + kk * 32);
  }

  union AF { bf16x8 v; u64 q[2]; };

  // flag of (producer WG p, wave w) at F[p*128 + w*32]; lane l covers chunk c's
  // producer WG c*64+l.
#define FADDR(c) (F + (((c) * 64 + l) * 128) + w * 32)
#define WAITV(vv, c)                                                        \
  { while (vv < t) { __builtin_amdgcn_s_sleep(1); vv = AL(FADDR(c)); } }
#define LD8(BUF, CH)                                                        \
  { _Pragma("unroll")                                                       \
    for (int r = 0; r < 8; ++r)                                             \
      BUF[r].v = *(const bf16x8*)(hp + (CH) * 256 + r * 32); }
#define MM8(BUF, W0)                                                        \
  { _Pragma("unroll")                                                       \
    for (int r = 0; r < 8; ++r) {                                           \
      bf16x8 b = *(const bf16x8*)(bx + ((W0) + r) * 576);                   \
      acc = __builtin_amdgcn_mfma_f32_16x16x32_bf16(BUF[r].v, b, acc, 0, 0, 0); \
    } }

  #pragma unroll 1
  for (int t = 0; t < NSTEP; ++t) {
    AF ha[8], hb[8];
    const u16* hp = H + (size_t)t * 65536 + (size_t)arow * 1024 + lk * 8;
    // issue ALL 4 chunk-flag loads concurrently (one far RT covers them all)
    int v0 = AL(FADDR(0));
    int v1 = AL(FADDR(1));
    int v2 = AL(FADDR(2));
    int v3 = AL(FADDR(3));
    // x-projection from prefetched ax (hides the flag round trip)
    f32x4 acc = { bias, bias, bias, bias };
    #pragma unroll
    for (int kk = 0; kk < 16; ++kk) {
      bf16x8 b = *(const bf16x8*)(bx + kk * 576);
      acc = __builtin_amdgcn_mfma_f32_16x16x32_bf16(ax[kk], b, acc, 0, 0, 0);
    }
    // per-chunk readiness: register compare fast path, woven re-poll for laggards
    WAITV(v0, 0);
    LD8(ha, 0);
    WAITV(v1, 1);
    LD8(hb, 1);
    MM8(ha, 16);
    WAITV(v2, 2);
    LD8(ha, 2);
    MM8(hb, 24);
    WAITV(v3, 3);
    LD8(hb, 3);
    MM8(ha, 32);
    MM8(hb, 40);

    // activations + state update; lanes lr<4 own (rows lk*4+r, col lr)
    float hv4[4], cn4[4];
    #pragma unroll
    for (int r = 0; r < 4; ++r) {
      float xv = acc[r];
      float act = sca / (1.f + __expf(-sca * xv)) + bd;  // sigmoid / tanh
      float gg = __shfl_xor(act, 8);
      float ff = __shfl_xor(act, 4);
      float oo = __shfl_xor(act, 12);
      float cn = ff * cst[r] + act * gg;   // act = i at lanes lr<4
      cst[r] = cn;
      float tc = 2.f / (1.f + __expf(-2.f * cn)) - 1.f;
      hv4[r] = oo * tc;
      cn4[r] = cn;
    }

    if (t == NSTEP - 1) {
      if (lr < 4) {
        #pragma unroll
        for (int r = 0; r < 4; ++r) {
          int R = w * 16 + lk * 4 + r;
          out[(size_t)R * 1024 + j * 4 + lr]          = hv4[r];
          out[65536 + (size_t)R * 1024 + j * 4 + lr]  = hv4[r];
          out[131072 + (size_t)R * 1024 + j * 4 + lr] = cn4[r];
        }
      }
    } else {
      // pack wave's 16x4 h tile in LDS (same-wave ds ops are in-order; no barrier)
      if (lr < 4) {
        #pragma unroll
        for (int r = 0; r < 4; ++r) hx[w][lk * 4 + r][lr] = f2bf(hv4[r]);
      }
      if (l < 16) {
        u64 pk = *(const u64*)(&hx[w][l][0]);
        u16* hw = H + (size_t)(t + 1) * 65536 + (size_t)(w * 16 + l) * 1024 + j * 4;
        AS((u64*)hw, pk);
      }
      // this wave's h stores reach L3, then publish this wave's epoch flag
      asm volatile("s_waitcnt vmcnt(0)" ::: "memory");
      if (l == 0) AS(F + j * 128 + w * 32, t + 1);
      // prefetch A1 for t+1 (fills under next step's flag wait + x-proj)
      {
        const u16* apre = A1 + ((size_t)(t + 1) * 64 + arow) * 512 + lk * 8;
        #pragma unroll
        for (int kk = 0; kk < 16; ++kk) ax[kk] = *(const bf16x8*)(apre + kk * 32);
      }
    }
  }
#undef FADDR
#undef WAITV
#undef LD8
#undef MM8
}

extern "C" void kernel_launch(void* const* d_in, const int* in_sizes, int n_in,
                              void* d_out, int out_size, void* d_ws, size_t ws_size,
                              hipStream_t stream) {
  const int*   sent = (const int*)d_in[0];
  const float* emb  = (const float*)d_in[1];
  const float* w_ih = (const float*)d_in[2];
  const float* w_hh = (const float*)d_in[3];
  const float* b_ih = (const float*)d_in[4];
  const float* b_hh = (const float*)d_in[5];
  float* out = (float*)d_out;

  // A1 32Mi | H 512 x 128Ki = 64Mi | F 128Ki  (~96.2 MiB; r15-proven available)
  char* ws = (char*)d_ws;
  u16* A1 = (u16*)ws;
  u16* H  = (u16*)(ws + 33554432);
  int* F  = (int*)(ws + 33554432 + 67108864);

  prep_kernel<<<256, 256, 0, stream>>>((u64*)H, F);
  gather_kernel<<<8192, 256, 0, stream>>>(sent, emb, A1);

  void* args[] = { (void*)&A1, (void*)&w_ih, (void*)&w_hh,
                   (void*)&b_ih, (void*)&b_hh, (void*)&H, (void*)&out, (void*)&F };
  hipError_t err = hipLaunchCooperativeKernel((void*)lstm_kernel, dim3(256), dim3(256),
                                              args, 0, stream);
  if (err != hipSuccess) {
    // dataflow kernel needs co-residency only; 2-blocks/CU envelope on 256 CUs
    lstm_kernel<<<dim3(256), dim3(256), 0, stream>>>(A1, w_ih, w_hh, b_ih, b_hh,
                                                     H, out, F);
  }
}